// Round 1
// baseline (671.368 us; speedup 1.0000x reference)
//
#include <hip/hip_runtime.h>

// NSDE pricer, R5: occupancy restructure (2 waves/SIMD).
// 32768 rows (path*64+opt). Wave = 16 rows (ONE 16x16 M-tile), block = 256 thr
// = 4 waves = 1 path, grid = 512 -> 2048 waves = 2/SIMD (256-VGPR cap via
// __launch_bounds__(256,2)). R4 was 1024 waves = 1/SIMD with VALUBusy 67.7%:
// dependent-chain stalls (tanh exp2->rcp, LDS S/V round-trip, shfl reduce)
// were exposed. Second resident wave per SIMD hides them.
// Layer2 (64x64) per net = 8x mfma_f32_16x16x32_bf16; W1 resident as bf16
// B-frags in 128 VGPRs. Layer1/3 + tanh in fp32 VALU. S,V in per-wave LDS
// slices -> no __syncthreads in the 32-step loop. Only h1 and W1 are bf16.

#define N_PATHS 512
#define N_STEPS 32
#define B_OPTS  64
#define HID     64

typedef __attribute__((ext_vector_type(8))) short bf16x8;   // 8 bf16 (4 VGPRs)
typedef __attribute__((ext_vector_type(4))) float f32x4;

__device__ __forceinline__ float fast_tanh(float x) {
    // tanh(x) = 1 - 2/(e^{2x}+1); exp2-based, correct saturation at +/-inf.
    float u = __builtin_amdgcn_exp2f(x * 2.8853900817779268f);
    float r = __builtin_amdgcn_rcpf(u + 1.0f);
    return fmaf(-2.0f, r, 1.0f);
}

__device__ __forceinline__ short f2bf(float f) {            // fp32 -> bf16 RNE
    union { float f; unsigned u; } c; c.f = f;
    unsigned u = c.u + 0x7FFFu + ((c.u >> 16) & 1u);
    return (short)(u >> 16);
}

__device__ __forceinline__ float select4(float a0, float a1, float a2, float a3, int idx) {
    float lo = (idx & 1) ? a1 : a0;
    float hi = (idx & 1) ? a3 : a2;
    return (idx & 2) ? hi : lo;
}

// Two nets of one phase: layer1 (VALU, A-layout), layer2 (MFMA), layer3+tanh.
// fout[nn][reg] = f for row (4q + reg) of this wave's 16-row tile, all lanes
// of the q-group valid after the shfl reduce.
__device__ __forceinline__ void mlp_pair(
    int base, int q, int nh,
    float Sa, float Va, float tA,
    const float4* __restrict__ w0t4,            // LDS, [4][72] swizzled
    const bf16x8 (&bfr)[4][4][2],
    const float (&b1v)[4][4], const float (&w2v)[4][4], const float (&b2s)[4],
    float (&fout)[2][4])
{
#pragma unroll
    for (int nn = 0; nn < 2; ++nn) {
        const int net = base + nn;
        // ---- layer1 in A-fragment layout: lane holds h1[row=nh][k=32kh+8q+j]
        bf16x8 afr[2];                           // [kh]
#pragma unroll
        for (int kh = 0; kh < 2; ++kh) {
#pragma unroll
            for (int j = 0; j < 8; ++j) {
                const int kk = kh * 32 + q * 8 + j;
                const float4 w = w0t4[net * 72 + kk + (kk >> 3)]; // bank-swizzled
                float a = fmaf(Sa, w.x, fmaf(Va, w.y, fmaf(tA, w.z, w.w)));
                afr[kh][j] = f2bf(fast_tanh(a));
            }
        }
        // ---- layer2: 1 M-tile x 4 N-tiles x 2 K-halves
        f32x4 C[4];
#pragma unroll
        for (int nt = 0; nt < 4; ++nt) {
            f32x4 c = {0.0f, 0.0f, 0.0f, 0.0f};
            c = __builtin_amdgcn_mfma_f32_16x16x32_bf16(afr[0], bfr[net][nt][0], c, 0, 0, 0);
            c = __builtin_amdgcn_mfma_f32_16x16x32_bf16(afr[1], bfr[net][nt][1], c, 0, 0, 0);
            C[nt] = c;
        }
        // ---- layer3: tanh, dot with W2 over nt, reduce over 16 C-columns
#pragma unroll
        for (int reg = 0; reg < 4; ++reg) {
            float s = 0.0f;
#pragma unroll
            for (int nt = 0; nt < 4; ++nt)
                s = fmaf(fast_tanh(C[nt][reg] + b1v[net][nt]), w2v[net][nt], s);
            s += __shfl_xor(s, 1);
            s += __shfl_xor(s, 2);
            s += __shfl_xor(s, 4);
            s += __shfl_xor(s, 8);
            fout[nn][reg] = s + b2s[net];
        }
    }
}

__global__ __launch_bounds__(256, 2) void nsde_kernel(
    const float* __restrict__ S0p, const float* __restrict__ Kp,
    const float* __restrict__ Tp,  const float* __restrict__ rfp,
    const float* __restrict__ Z1,  const float* __restrict__ Z2,
    const float* __restrict__ W0,  const float* __restrict__ b0,
    const float* __restrict__ W1,  const float* __restrict__ b1,
    const float* __restrict__ W2,  const float* __restrict__ b2,
    float* __restrict__ out, float* __restrict__ ws, int use_ws)
{
    const int tid  = threadIdx.x;
    const int wave = tid >> 6;
    const int lane = tid & 63;
    const int q    = lane >> 4;
    const int nh   = lane & 15;
    const int path = blockIdx.x;                    // one path per block

    __shared__ float  S_lds[64], V_lds[64];
    __shared__ float4 w0t4[4 * 72];                 // swizzled (w_S,w_V,w_t, b0+rf*w_rf)

    const float rf = rfp[0];

    // ---- one-time staging ----
    {
        const int net = tid >> 6, kk = tid & 63;
        const float wsv = W0[net * 256 + 0 * 64 + kk];
        const float wvv = W0[net * 256 + 1 * 64 + kk];
        const float wrv = W0[net * 256 + 2 * 64 + kk];
        const float wtv = W0[net * 256 + 3 * 64 + kk];
        w0t4[net * 72 + kk + (kk >> 3)] =
            make_float4(wsv, wvv, wtv, fmaf(rf, wrv, b0[net * 64 + kk]));
    }
    if (tid < 64) { S_lds[tid] = S0p[tid]; V_lds[tid] = 0.2f; }

    // ---- per-lane constants ----
    const int oA = wave * 16 + nh;                  // A-layout row (opt index)
    const int oW = wave * 16 + 4 * q + (nh & 3);    // writer row
    const float dta = Tp[oA] * (1.0f / N_STEPS);
    const float dtw = Tp[oW] * (1.0f / N_STEPS);
    const float sqw = sqrtf(dtw);

    float b1v[4][4], w2v[4][4], b2s[4];
#pragma unroll
    for (int net = 0; net < 4; ++net) {
        b2s[net] = b2[net];
#pragma unroll
        for (int nt = 0; nt < 4; ++nt) {
            b1v[net][nt] = b1[net * 64 + nt * 16 + nh];
            w2v[net][nt] = W2[net * 64 + nt * 16 + nh];
        }
    }

    // ---- W1 -> resident bf16 B-fragments: B[k=32kh+8q+j][n=16nt+nh] ----
    bf16x8 bfr[4][4][2];
#pragma unroll
    for (int net = 0; net < 4; ++net)
#pragma unroll
        for (int nt = 0; nt < 4; ++nt)
#pragma unroll
            for (int kh = 0; kh < 2; ++kh)
#pragma unroll
                for (int j = 0; j < 8; ++j)
                    bfr[net][nt][kh][j] = f2bf(
                        W1[net * 4096 + (kh * 32 + q * 8 + j) * 64 + nt * 16 + nh]);

    __syncthreads();

    const float* __restrict__ z1p = Z1 + path * N_STEPS;
    const float* __restrict__ z2p = Z2 + path * N_STEPS;

    for (int step = 0; step < N_STEPS; ++step) {
        const float z1 = z1p[step];
        const float z2 = z2p[step];
        const float tA = dta * (float)step;

        // ---- phase 1: nets 0,1 on (S, V, rf, t) ----
        float Sa = S_lds[oA];
        const float Va = V_lds[oA];
        float f[2][4];
        mlp_pair(0, q, nh, Sa, Va, tA, w0t4, bfr, b1v, w2v, b2s, f);

        {   // S update, writer lanes nh<4 handle rows 4q+nh
            const int r = nh & 3;
            const float f0 = select4(f[0][0], f[0][1], f[0][2], f[0][3], r);
            const float f1 = select4(f[1][0], f[1][1], f[1][2], f[1][3], r);
            const float Sn = S_lds[oW] * fmaf(f1, z1, fmaf(f0, dtw, 1.0f));
            if (nh < 4) S_lds[oW] = Sn;
        }

        // ---- phase 2: nets 2,3 on (S_new, V, rf, t) ----
        Sa = S_lds[oA];                             // updated S, same wave
        float g[2][4];
        mlp_pair(2, q, nh, Sa, Va, tA, w0t4, bfr, b1v, w2v, b2s, g);

        {
            const int r = nh & 3;
            const float g0 = select4(g[0][0], g[0][1], g[0][2], g[0][3], r);
            const float g1 = select4(g[1][0], g[1][1], g[1][2], g[1][3], r);
            const float Vn = V_lds[oW] * fmaf(g1, sqw * z2, fmaf(g0, dtw, 1.0f));
            if (nh < 4) V_lds[oW] = Vn;
        }
    }

    // ---- payoff: block partial per option ----
    __syncthreads();
    if (tid < 64) {
        const float Tt   = Tp[tid];
        const float disc = __builtin_amdgcn_exp2f(-rf * Tt * 1.4426950408889634f)
                           * (1.0f / (float)N_PATHS);
        const float Kv = Kp[tid];
        const float s1 = S_lds[tid];
        const float p1 = (s1 - Kv < 0.0f) ? 0.0f : s1;
        const float v  = disc * p1;
        if (use_ws) ws[path * 64 + tid] = v;
        else        atomicAdd(&out[tid], v);
    }
}

__global__ void reduce_kernel(const float* __restrict__ ws, float* __restrict__ out) {
    __shared__ float acc[4][64];
    const int o = threadIdx.x & 63, g = threadIdx.x >> 6;
    float s = 0.0f;
    for (int b = g; b < N_PATHS; b += 4) s += ws[b * 64 + o];
    acc[g][o] = s;
    __syncthreads();
    if (threadIdx.x < 64)
        out[threadIdx.x] = acc[0][threadIdx.x] + acc[1][threadIdx.x]
                         + acc[2][threadIdx.x] + acc[3][threadIdx.x];
}

__global__ void zero_out_kernel(float* __restrict__ out) {
    out[threadIdx.x] = 0.0f;
}

extern "C" void kernel_launch(void* const* d_in, const int* in_sizes, int n_in,
                              void* d_out, int out_size, void* d_ws, size_t ws_size,
                              hipStream_t stream) {
    const float* S0p = (const float*)d_in[0];
    const float* Kp  = (const float*)d_in[1];
    const float* Tp  = (const float*)d_in[2];
    const float* rfp = (const float*)d_in[3];
    const float* Z1  = (const float*)d_in[4];
    const float* Z2  = (const float*)d_in[5];
    const float* W0  = (const float*)d_in[6];
    const float* b0  = (const float*)d_in[7];
    const float* W1  = (const float*)d_in[8];
    const float* b1  = (const float*)d_in[9];
    const float* W2  = (const float*)d_in[10];
    const float* b2  = (const float*)d_in[11];
    float* out = (float*)d_out;
    float* wsf = (float*)d_ws;

    const int use_ws = (ws_size >= (size_t)(N_PATHS * 64 * sizeof(float))) ? 1 : 0;

    if (!use_ws) zero_out_kernel<<<1, B_OPTS, 0, stream>>>(out);
    nsde_kernel<<<N_PATHS, 256, 0, stream>>>(S0p, Kp, Tp, rfp, Z1, Z2,
                                             W0, b0, W1, b1, W2, b2, out, wsf, use_ws);
    if (use_ws) reduce_kernel<<<1, 256, 0, stream>>>(wsf, out);
}

// Round 3
// 371.766 us; speedup vs baseline: 1.8059x; 1.8059x over previous
//
#include <hip/hip_runtime.h>

// NSDE pricer, R6b: resubmit of R6 (bench infra failed twice; no counters).
// 2 waves/SIMD + W1 in LDS (fragment-ordered).
// R5 post-mortem: __launch_bounds__(256,2) forced VGPR 128 -> compiler spilled
// the 128-VGPR register-resident W1 (bfr) to scratch -> 1.68 GB HBM reload
// traffic (39% of peak), 585 us. Fix: W1 lives in LDS as bf16 B-fragments in
// lane-contiguous order (lane l reads base + l*16 B, conflict-free
// ds_read_b128, compile-time offsets). Register need drops to ~150-190 ->
// fits 256/wave naturally -> 2 waves/SIMD with grid 512 x 4 waves.
// Wave = 16 rows (one 16x16 M-tile), block = 256 thr = 4 waves = 1 path.
// Layer2 (64x64) per net = 8x mfma_f32_16x16x32_bf16. Layer1/3 + tanh in
// fp32 VALU. S,V in per-wave LDS slices -> no __syncthreads in step loop.

#define N_PATHS 512
#define N_STEPS 32
#define B_OPTS  64
#define HID     64

typedef __attribute__((ext_vector_type(8))) short bf16x8;   // 8 bf16 (4 VGPRs)
typedef __attribute__((ext_vector_type(4))) float f32x4;

__device__ __forceinline__ float fast_tanh(float x) {
    // tanh(x) = 1 - 2/(e^{2x}+1); exp2-based, correct saturation at +/-inf.
    float u = __builtin_amdgcn_exp2f(x * 2.8853900817779268f);
    float r = __builtin_amdgcn_rcpf(u + 1.0f);
    return fmaf(-2.0f, r, 1.0f);
}

__device__ __forceinline__ short f2bf(float f) {            // fp32 -> bf16 RNE
    union { float f; unsigned u; } c; c.f = f;
    unsigned u = c.u + 0x7FFFu + ((c.u >> 16) & 1u);
    return (short)(u >> 16);
}

__device__ __forceinline__ float select4(float a0, float a1, float a2, float a3, int idx) {
    float lo = (idx & 1) ? a1 : a0;
    float hi = (idx & 1) ? a3 : a2;
    return (idx & 2) ? hi : lo;
}

// Two nets of one phase: layer1 (VALU, A-layout), layer2 (MFMA, W1 frags from
// LDS), layer3+tanh. fout[nn][reg] = f for row (4q + reg) of this wave's
// 16-row tile, all lanes valid after the shfl reduce.
__device__ __forceinline__ void mlp_pair(
    int base, int q, int nh,
    float Sa, float Va, float tA,
    const float4* __restrict__ w0t4,            // LDS, [4][72] swizzled
    const uint4* __restrict__ w1p,              // LDS frags, pre-offset by lane
    const float (&b1v)[4][4], const float (&w2v)[4][4], const float (&b2s)[4],
    float (&fout)[2][4])
{
#pragma unroll
    for (int nn = 0; nn < 2; ++nn) {
        const int net = base + nn;
        // ---- layer1 in A-fragment layout: lane holds h1[row=nh][k=32kh+8q+j]
        bf16x8 afr[2];                           // [kh]
#pragma unroll
        for (int kh = 0; kh < 2; ++kh) {
#pragma unroll
            for (int j = 0; j < 8; ++j) {
                const int kk = kh * 32 + q * 8 + j;
                const float4 w = w0t4[net * 72 + kk + (kk >> 3)]; // bank-swizzled
                float a = fmaf(Sa, w.x, fmaf(Va, w.y, fmaf(tA, w.z, w.w)));
                afr[kh][j] = f2bf(fast_tanh(a));
            }
        }
        // ---- layer2: 1 M-tile x 4 N-tiles x 2 K-halves, W1 frags via
        // ds_read_b128 (lane-contiguous, conflict-free, immediate offsets)
        f32x4 C[4];
#pragma unroll
        for (int nt = 0; nt < 4; ++nt) {
            const bf16x8 bf0 = __builtin_bit_cast(bf16x8, w1p[((net * 4 + nt) * 2 + 0) * 64]);
            const bf16x8 bf1 = __builtin_bit_cast(bf16x8, w1p[((net * 4 + nt) * 2 + 1) * 64]);
            f32x4 c = {0.0f, 0.0f, 0.0f, 0.0f};
            c = __builtin_amdgcn_mfma_f32_16x16x32_bf16(afr[0], bf0, c, 0, 0, 0);
            c = __builtin_amdgcn_mfma_f32_16x16x32_bf16(afr[1], bf1, c, 0, 0, 0);
            C[nt] = c;
        }
        // ---- layer3: tanh, dot with W2 over nt, reduce over 16 C-columns
#pragma unroll
        for (int reg = 0; reg < 4; ++reg) {
            float s = 0.0f;
#pragma unroll
            for (int nt = 0; nt < 4; ++nt)
                s = fmaf(fast_tanh(C[nt][reg] + b1v[net][nt]), w2v[net][nt], s);
            s += __shfl_xor(s, 1);
            s += __shfl_xor(s, 2);
            s += __shfl_xor(s, 4);
            s += __shfl_xor(s, 8);
            fout[nn][reg] = s + b2s[net];
        }
    }
}

__global__ __launch_bounds__(256) void nsde_kernel(
    const float* __restrict__ S0p, const float* __restrict__ Kp,
    const float* __restrict__ Tp,  const float* __restrict__ rfp,
    const float* __restrict__ Z1,  const float* __restrict__ Z2,
    const float* __restrict__ W0,  const float* __restrict__ b0,
    const float* __restrict__ W1,  const float* __restrict__ b1,
    const float* __restrict__ W2,  const float* __restrict__ b2,
    float* __restrict__ out, float* __restrict__ ws, int use_ws)
{
    const int tid  = threadIdx.x;
    const int wave = tid >> 6;
    const int lane = tid & 63;
    const int q    = lane >> 4;
    const int nh   = lane & 15;
    const int path = blockIdx.x;                    // one path per block

    __shared__ float  S_lds[64], V_lds[64];
    __shared__ float4 w0t4[4 * 72];                 // swizzled (w_S,w_V,w_t, b0+rf*w_rf)
    __shared__ uint4  w1f[2048];                    // W1 bf16 frags, 32 KB
                                                    // [net][nt][kh] x [q][nh]

    const float rf = rfp[0];

    // ---- one-time staging: W0 columns ----
    {
        const int net = tid >> 6, kk = tid & 63;
        const float wsv = W0[net * 256 + 0 * 64 + kk];
        const float wvv = W0[net * 256 + 1 * 64 + kk];
        const float wrv = W0[net * 256 + 2 * 64 + kk];
        const float wtv = W0[net * 256 + 3 * 64 + kk];
        w0t4[net * 72 + kk + (kk >> 3)] =
            make_float4(wsv, wvv, wtv, fmaf(rf, wrv, b0[net * 64 + kk]));
    }
    if (tid < 64) { S_lds[tid] = S0p[tid]; V_lds[tid] = 0.2f; }

    // ---- one-time staging: W1 -> LDS bf16 B-fragments ----
    // frag f: nh=f&15, q=(f>>4)&3, kh=(f>>6)&1, nt=(f>>7)&3, net=(f>>9)&3
    // holds B[k=32kh+8q+j][n=16nt+nh], j=0..7 packed (16 B).
#pragma unroll
    for (int it = 0; it < 8; ++it) {
        const int f   = it * 256 + tid;
        const int fnh = f & 15;
        const int fq  = (f >> 4) & 3;
        const int fkh = (f >> 6) & 1;
        const int fnt = (f >> 7) & 3;
        const int fnet= (f >> 9) & 3;
        const float* wp = W1 + fnet * 4096 + (fkh * 32 + fq * 8) * 64 + fnt * 16 + fnh;
        bf16x8 fr;
#pragma unroll
        for (int j = 0; j < 8; ++j) fr[j] = f2bf(wp[j * 64]);
        w1f[f] = __builtin_bit_cast(uint4, fr);
    }

    // ---- per-lane constants ----
    const int oA = wave * 16 + nh;                  // A-layout row (opt index)
    const int oW = wave * 16 + 4 * q + (nh & 3);    // writer row
    const float dta = Tp[oA] * (1.0f / N_STEPS);
    const float dtw = Tp[oW] * (1.0f / N_STEPS);
    const float sqw = sqrtf(dtw);

    float b1v[4][4], w2v[4][4], b2s[4];
#pragma unroll
    for (int net = 0; net < 4; ++net) {
        b2s[net] = b2[net];
#pragma unroll
        for (int nt = 0; nt < 4; ++nt) {
            b1v[net][nt] = b1[net * 64 + nt * 16 + nh];
            w2v[net][nt] = W2[net * 64 + nt * 16 + nh];
        }
    }

    __syncthreads();

    const uint4* __restrict__ w1p = &w1f[q * 16 + nh];  // lane-contiguous base
    const float* __restrict__ z1p = Z1 + path * N_STEPS;
    const float* __restrict__ z2p = Z2 + path * N_STEPS;

    for (int step = 0; step < N_STEPS; ++step) {
        const float z1 = z1p[step];
        const float z2 = z2p[step];
        const float tA = dta * (float)step;

        // ---- phase 1: nets 0,1 on (S, V, rf, t) ----
        float Sa = S_lds[oA];
        const float Va = V_lds[oA];
        float f[2][4];
        mlp_pair(0, q, nh, Sa, Va, tA, w0t4, w1p, b1v, w2v, b2s, f);

        {   // S update, writer lanes nh<4 handle rows 4q+nh
            const int r = nh & 3;
            const float f0 = select4(f[0][0], f[0][1], f[0][2], f[0][3], r);
            const float f1 = select4(f[1][0], f[1][1], f[1][2], f[1][3], r);
            const float Sn = S_lds[oW] * fmaf(f1, z1, fmaf(f0, dtw, 1.0f));
            if (nh < 4) S_lds[oW] = Sn;
        }

        // ---- phase 2: nets 2,3 on (S_new, V, rf, t) ----
        Sa = S_lds[oA];                             // updated S, same wave
        float g[2][4];
        mlp_pair(2, q, nh, Sa, Va, tA, w0t4, w1p, b1v, w2v, b2s, g);

        {
            const int r = nh & 3;
            const float g0 = select4(g[0][0], g[0][1], g[0][2], g[0][3], r);
            const float g1 = select4(g[1][0], g[1][1], g[1][2], g[1][3], r);
            const float Vn = V_lds[oW] * fmaf(g1, sqw * z2, fmaf(g0, dtw, 1.0f));
            if (nh < 4) V_lds[oW] = Vn;
        }
    }

    // ---- payoff: block partial per option ----
    __syncthreads();
    if (tid < 64) {
        const float Tt   = Tp[tid];
        const float disc = __builtin_amdgcn_exp2f(-rf * Tt * 1.4426950408889634f)
                           * (1.0f / (float)N_PATHS);
        const float Kv = Kp[tid];
        const float s1 = S_lds[tid];
        const float p1 = (s1 - Kv < 0.0f) ? 0.0f : s1;
        const float v  = disc * p1;
        if (use_ws) ws[path * 64 + tid] = v;
        else        atomicAdd(&out[tid], v);
    }
}

__global__ void reduce_kernel(const float* __restrict__ ws, float* __restrict__ out) {
    __shared__ float acc[4][64];
    const int o = threadIdx.x & 63, g = threadIdx.x >> 6;
    float s = 0.0f;
    for (int b = g; b < N_PATHS; b += 4) s += ws[b * 64 + o];
    acc[g][o] = s;
    __syncthreads();
    if (threadIdx.x < 64)
        out[threadIdx.x] = acc[0][threadIdx.x] + acc[1][threadIdx.x]
                         + acc[2][threadIdx.x] + acc[3][threadIdx.x];
}

__global__ void zero_out_kernel(float* __restrict__ out) {
    out[threadIdx.x] = 0.0f;
}

extern "C" void kernel_launch(void* const* d_in, const int* in_sizes, int n_in,
                              void* d_out, int out_size, void* d_ws, size_t ws_size,
                              hipStream_t stream) {
    const float* S0p = (const float*)d_in[0];
    const float* Kp  = (const float*)d_in[1];
    const float* Tp  = (const float*)d_in[2];
    const float* rfp = (const float*)d_in[3];
    const float* Z1  = (const float*)d_in[4];
    const float* Z2  = (const float*)d_in[5];
    const float* W0  = (const float*)d_in[6];
    const float* b0  = (const float*)d_in[7];
    const float* W1  = (const float*)d_in[8];
    const float* b1  = (const float*)d_in[9];
    const float* W2  = (const float*)d_in[10];
    const float* b2  = (const float*)d_in[11];
    float* out = (float*)d_out;
    float* wsf = (float*)d_ws;

    const int use_ws = (ws_size >= (size_t)(N_PATHS * 64 * sizeof(float))) ? 1 : 0;

    if (!use_ws) zero_out_kernel<<<1, B_OPTS, 0, stream>>>(out);
    nsde_kernel<<<N_PATHS, 256, 0, stream>>>(S0p, Kp, Tp, rfp, Z1, Z2,
                                             W0, b0, W1, b1, W2, b2, out, wsf, use_ws);
    if (use_ws) reduce_kernel<<<1, 256, 0, stream>>>(wsf, out);
}